// Round 5
// baseline (23601.501 us; speedup 1.0000x reference)
//
#include <hip/hip_runtime.h>

// LSTM encoder-decoder B=512 F=1024 HIST=20 FUT=30 L=3 (fp32 in/out).
// Round 8: round-6 GEMM (128^2 tiles, z=4, 2 blocks/CU, counted-vmcnt pipeline,
//   pre-split bf16 weights) + cell fused into epilogue, FENCE-FREE.
//   Round-7 post-mortem (counters): __threadfence() in all 512 blocks emitted
//   buffer_wbl2/inv (full L2 writeback per block) -> uniform 6.8x stall
//   (MfmaUtil 5%, VALUBusy 3%, HBM 475 GB/s; two 30ms outlier dispatches).
//   Fix: no fences. Partials written with agent-scope relaxed stores (commit to
//   device coherence point, no dirty cross-XCD L2); elected block reads them
//   with agent-scope relaxed loads (bypass stale L1/L2). Ordering via
//   __syncthreads (drains vmcnt) -> atomicAdd -> data-dependent reads.
//   Remap clusters each 16-block election group (4 gates x 4 z) on one XCD.

#define BDIM 512
#define FDIM 1024
#define HISTLEN 20
#define LAYERS 3
#define NG 4096
#define KD 1024
#define KSTEPS 16   // 512 k per block-chunk / BK=32
#define NCNT (150 * 32)   // per-layer-step arrival counters (32 groups each)

typedef __attribute__((ext_vector_type(8))) short short8;   // 8 bf16 = 4 VGPRs
typedef __attribute__((ext_vector_type(4))) float f32x4;    // MFMA accumulator
typedef __attribute__((ext_vector_type(4))) unsigned short u16x4;

__device__ __forceinline__ float sigf(float x) { return 1.f / (1.f + __expf(-x)); }
__device__ __forceinline__ float tanh_fast(float x) {
    float e = __expf(-2.f * fabsf(x));
    float r = (1.f - e) / (1.f + e);
    return copysignf(r, x);
}
__device__ __forceinline__ ushort bfhi(float w) { return (ushort)(__float_as_uint(w) >> 16); }
__device__ __forceinline__ float hif(float w) { return __uint_as_float(__float_as_uint(w) & 0xFFFF0000u); }
__device__ __forceinline__ ushort bflo(float w) { return bfhi(w - hif(w)); }

__device__ __forceinline__ void gl16(const ushort* g, ushort* l) {
    __builtin_amdgcn_global_load_lds(
        (const __attribute__((address_space(1))) unsigned int*)g,
        (__attribute__((address_space(3))) unsigned int*)l, 16, 0, 0);
}

__device__ __forceinline__ void s_agent(float* p, float v) {
    __hip_atomic_store(p, v, __ATOMIC_RELAXED, __HIP_MEMORY_SCOPE_AGENT);
}
__device__ __forceinline__ float l_agent(const float* p) {
    return __hip_atomic_load(p, __ATOMIC_RELAXED, __HIP_MEMORY_SCOPE_AGENT);
}

// ---------------- one-time weight pre-split: fp32 W -> bf16 hi/lo --------------
__global__ void prep_w(const float* __restrict__ Wih, const float* __restrict__ Whh,
                       ushort* __restrict__ Whi, ushort* __restrict__ Wlo)
{
    size_t i4 = ((size_t)blockIdx.x * 256 + threadIdx.x) * 4;
    size_t slot = i4 >> 22;
    size_t off  = i4 & 0x3FFFFFu;
    const float* src = ((slot & 1) ? Whh : Wih) + ((slot >> 1) << 22) + off;
    float4 v = *(const float4*)src;
    u16x4 hi, lo;
    #pragma unroll
    for (int e = 0; e < 4; ++e) {
        float w = ((const float*)&v)[e];
        unsigned u = __float_as_uint(w);
        hi[e] = (ushort)(u >> 16);
        float r = w - __uint_as_float(u & 0xFFFF0000u);
        lo[e] = (ushort)(__float_as_uint(r) >> 16);
    }
    *(u16x4*)(Whi + i4) = hi;
    *(u16x4*)(Wlo + i4) = lo;
}

// ---------------- GEMM + fused cell epilogue (fence-free) ----------------------
// Remap: lb -> xcd=lb&7, slot=lb>>3; q=slot>>4, mem=slot&15; z=mem&3, gt=mem>>2;
// gid=xcd*4+q (0..31); by=gid>>3, fb=gid&7; bx=gt*8+fb.  Bijective; the 16
// blocks of election group gid (4 gates x 4 z) share one XCD.
__global__ __launch_bounds__(256, 2) void gemm_cell(
    const ushort* __restrict__ A0hi, const ushort* __restrict__ A0lo,
    const ushort* __restrict__ W0hi, const ushort* __restrict__ W0lo,
    const ushort* __restrict__ A1hi, const ushort* __restrict__ A1lo,
    const ushort* __restrict__ W1hi, const ushort* __restrict__ W1lo,
    float* __restrict__ gp, int* __restrict__ cnt,
    const float* __restrict__ bi, const float* __restrict__ bh,
    float* __restrict__ c, ushort* __restrict__ Hhi, ushort* __restrict__ Hlo,
    float* __restrict__ y, int t, int fut)
{
    // [buf][tile: Ahi,Alo,Whi,Wlo][128*32 bf16] = 64 KB total
    __shared__ __attribute__((aligned(16))) ushort lds[2][4][4096];
    __shared__ int elect;

    const int lb   = blockIdx.x + 32 * blockIdx.y + 128 * blockIdx.z;  // 0..511
    const int xcd  = lb & 7;
    const int slot = lb >> 3;
    const int q    = slot >> 4;
    const int mem  = slot & 15;
    const int z    = mem & 3;
    const int gt   = mem >> 2;
    const int gid  = xcd * 4 + q;
    const int by   = gid >> 3;
    const int fb   = gid & 7;
    const int bx   = gt * 8 + fb;

    const int s  = z & 1;
    const int kh = z >> 1;
    const ushort* Ahi = s ? A1hi : A0hi;
    const ushort* Alo = s ? A1lo : A0lo;
    const ushort* Whi = s ? W1hi : W0hi;
    const ushort* Wlo = s ? W1lo : W0lo;
    float* out = gp + (size_t)z * BDIM * NG;

    const int tid = threadIdx.x;
    const int m0 = by * 128;
    const int n0 = bx * 128;

    const int srow = tid >> 2;
    const int scol = ((tid & 3) ^ ((srow >> 1) & 3)) << 3;   // bf16 elems
    const int kbeg = kh * (KD / 2);

    const ushort* pAhi = Ahi + (size_t)(m0 + srow) * KD + kbeg + scol;
    const ushort* pAlo = Alo + (size_t)(m0 + srow) * KD + kbeg + scol;
    const ushort* pWhi = Whi + (size_t)(n0 + srow) * KD + kbeg + scol;
    const ushort* pWlo = Wlo + (size_t)(n0 + srow) * KD + kbeg + scol;
    const int rstep = 64 * KD;

    const int lane = tid & 63;
    const int wid  = tid >> 6;
    const int wm = (wid & 1) * 64;
    const int wn = (wid >> 1) * 64;
    const int frow = lane & 15;
    const int oct  = lane >> 4;

    int a_e[4], w_e[4];
    #pragma unroll
    for (int i = 0; i < 4; ++i) {
        int ra = wm + i * 16 + frow;
        a_e[i] = ra * 32 + (((oct ^ (ra >> 1)) & 3) << 3);
        int rw = wn + i * 16 + frow;
        w_e[i] = rw * 32 + (((oct ^ (rw >> 1)) & 3) << 3);
    }

    f32x4 acc[4][4] = {};

    auto STAGE = [&](ushort* buf, int kk) {
        ushort* d0 = buf + tid * 8;
        gl16(pAhi + kk,         d0);
        gl16(pAlo + kk,         d0 + 4096);
        gl16(pWhi + kk,         d0 + 8192);
        gl16(pWlo + kk,         d0 + 12288);
        ushort* d1 = d0 + 2048;
        gl16(pAhi + rstep + kk, d1);
        gl16(pAlo + rstep + kk, d1 + 4096);
        gl16(pWhi + rstep + kk, d1 + 8192);
        gl16(pWlo + rstep + kk, d1 + 12288);
    };

    auto COMPUTE = [&](const ushort* buf) {
        short8 fah[4], fal[4], fbh[4], fbl[4];
        #pragma unroll
        for (int i = 0; i < 4; ++i) {
            fah[i] = *(const short8*)(buf + a_e[i]);
            fal[i] = *(const short8*)(buf + 4096 + a_e[i]);
            fbh[i] = *(const short8*)(buf + 8192 + w_e[i]);
            fbl[i] = *(const short8*)(buf + 12288 + w_e[i]);
        }
        asm volatile("s_waitcnt lgkmcnt(0)" ::: "memory");
        __builtin_amdgcn_sched_barrier(0);
        __builtin_amdgcn_s_barrier();
        __builtin_amdgcn_sched_barrier(0);
        __builtin_amdgcn_s_setprio(1);
        #pragma unroll
        for (int j = 0; j < 4; ++j) {
            #pragma unroll
            for (int i = 0; i < 4; ++i) {
                acc[i][j] = __builtin_amdgcn_mfma_f32_16x16x32_bf16(fah[i], fbh[j], acc[i][j], 0, 0, 0);
                acc[i][j] = __builtin_amdgcn_mfma_f32_16x16x32_bf16(fal[i], fbh[j], acc[i][j], 0, 0, 0);
                acc[i][j] = __builtin_amdgcn_mfma_f32_16x16x32_bf16(fah[i], fbl[j], acc[i][j], 0, 0, 0);
            }
        }
        __builtin_amdgcn_s_setprio(0);
    };

    STAGE(&lds[0][0][0], 0);
    #pragma unroll 1
    for (int t2 = 0; t2 < KSTEPS - 1; ++t2) {
        STAGE(&lds[(t2 + 1) & 1][0][0], (t2 + 1) * 32);
        asm volatile("s_waitcnt vmcnt(8)" ::: "memory");
        __builtin_amdgcn_sched_barrier(0);
        __builtin_amdgcn_s_barrier();
        __builtin_amdgcn_sched_barrier(0);
        COMPUTE(&lds[t2 & 1][0][0]);
    }
    asm volatile("s_waitcnt vmcnt(0)" ::: "memory");
    __builtin_amdgcn_s_barrier();
    COMPUTE(&lds[(KSTEPS - 1) & 1][0][0]);

    // partial C-write, agent-scope (device-coherent, no L2 dirty state).
    // C/D layout: row=(lane>>4)*4+reg, col=lane&15 (verified m89/m91)
    #pragma unroll
    for (int i = 0; i < 4; ++i) {
        #pragma unroll
        for (int j = 0; j < 4; ++j) {
            int col = n0 + wn + j * 16 + frow;
            #pragma unroll
            for (int r = 0; r < 4; ++r) {
                int row = m0 + wm + i * 16 + oct * 4 + r;
                s_agent(out + (size_t)row * NG + col, acc[i][j][r]);
            }
        }
    }

    // ---- fused cell epilogue: last of 16 blocks (4 gates x 4 z) per group -----
    __syncthreads();                       // drains vmcnt(0) -> stores committed
    if (tid == 0) elect = atomicAdd(cnt + gid, 1);
    __syncthreads();
    if (elect != 15) return;

    const int fbase = fb * 128;
    const size_t MN = (size_t)BDIM * NG;
    const int rr = tid >> 5;               // 0..7
    const int f4 = fbase + (tid & 31) * 4;
    #pragma unroll 1
    for (int p = 0; p < 16; ++p) {
        const int r = m0 + p * 8 + rr;
        const size_t rowb = (size_t)r * NG;
        float g[4][4];
        #pragma unroll
        for (int gq = 0; gq < 4; ++gq)
            #pragma unroll
            for (int e = 0; e < 4; ++e)
                g[gq][e] = bi[gq * FDIM + f4 + e] + bh[gq * FDIM + f4 + e];
        #pragma unroll
        for (int zz = 0; zz < 4; ++zz) {
            const float* gz = gp + (size_t)zz * MN + rowb;
            #pragma unroll
            for (int gq = 0; gq < 4; ++gq)
                #pragma unroll
                for (int e = 0; e < 4; ++e)
                    g[gq][e] += l_agent(gz + gq * FDIM + f4 + e);
        }
        const int idx = r * FDIM + f4;
        f32x4 cv = *(const f32x4*)(c + idx);
        f32x4 cn, hn;
        #pragma unroll
        for (int e = 0; e < 4; ++e) {
            cn[e] = sigf(g[1][e]) * cv[e] + sigf(g[0][e]) * tanh_fast(g[2][e]);
            hn[e] = sigf(g[3][e]) * tanh_fast(cn[e]);
        }
        *(f32x4*)(c + idx) = cn;
        u16x4 hh, hl;
        #pragma unroll
        for (int e = 0; e < 4; ++e) { hh[e] = bfhi(hn[e]); hl[e] = bflo(hn[e]); }
        *(u16x4*)(Hhi + idx) = hh;
        *(u16x4*)(Hlo + idx) = hl;
        if (y) {
            #pragma unroll
            for (int e = 0; e < 4; ++e) y[(size_t)(idx + e) * fut + t] = hn[e];
        }
    }
}

// x_t from seq [B,F,HIST] -> split bf16
__global__ void pack_split(const float* __restrict__ seq,
                           ushort* __restrict__ Xhi, ushort* __restrict__ Xlo, int t)
{
    int idx = blockIdx.x * blockDim.x + threadIdx.x;
    float v = seq[(size_t)idx * HISTLEN + t];
    Xhi[idx] = bfhi(v);
    Xlo[idx] = bflo(v);
}

// fp32 vector -> split bf16 (decoder t=0 input = c[2])
__global__ void split_vec(const float* __restrict__ src,
                          ushort* __restrict__ hi, ushort* __restrict__ lo)
{
    int idx = blockIdx.x * blockDim.x + threadIdx.x;
    float v = src[idx];
    hi[idx] = bfhi(v);
    lo[idx] = bflo(v);
}

extern "C" void kernel_launch(void* const* d_in, const int* in_sizes, int n_in,
                              void* d_out, int out_size, void* d_ws, size_t ws_size,
                              hipStream_t stream)
{
    const float* seq = (const float*)d_in[0];
    const float* Wih = (const float*)d_in[1];
    const float* Whh = (const float*)d_in[2];
    const float* bih = (const float*)d_in[3];
    const float* bhh = (const float*)d_in[4];
    float* out = (float*)d_out;

    const int fut = out_size / (BDIM * FDIM);           // 30
    const size_t BF = (size_t)BDIM * FDIM;
    const size_t MN = (size_t)BDIM * NG;
    const size_t Wsl = (size_t)1 << 22;                 // elems per (l,s) weight slot

    // ws: c[3BF]f32 | Hhi[3BF]u16 | Hlo | cnt[NCNT]i32 | Xhi[BF]u16 | Xlo |
    //     gp[4*MN]f32 | Whi[6*Wsl]u16 | Wlo[6*Wsl]u16   (~142 MiB)
    float*  c   = (float*)d_ws;
    ushort* Hhi = (ushort*)(c + LAYERS * BF);
    ushort* Hlo = Hhi + LAYERS * BF;
    int*    cnt = (int*)(Hlo + LAYERS * BF);
    ushort* Xhi = (ushort*)(cnt + NCNT);
    ushort* Xlo = Xhi + BF;
    float*  gp  = (float*)(Xlo + BF);
    ushort* Whi = (ushort*)(gp + 4 * MN);
    ushort* Wlo = Whi + 6 * Wsl;

    const size_t need = (size_t)((char*)(Wlo + 6 * Wsl) - (char*)d_ws);
    if (ws_size < need) return;                         // clean fail, no OOB

    // zero c, Hhi, Hlo, cnt in one shot
    hipMemsetAsync(d_ws, 0, LAYERS * BF * 8 + NCNT * 4, stream);
    prep_w<<<24576, 256, 0, stream>>>(Wih, Whh, Whi, Wlo);

    dim3 ggrid(NG / 128, BDIM / 128, 4);                // (32, 4, 4) = 512 WGs
    const int cgrid = (int)(BF / 256);

    int ls = 0;
    for (int t = 0; t < HISTLEN + fut; ++t) {
        const bool dec = (t >= HISTLEN);
        if (!dec) {
            pack_split<<<cgrid, 256, 0, stream>>>(seq, Xhi, Xlo, t);
        } else if (t == HISTLEN) {
            split_vec<<<cgrid, 256, 0, stream>>>(c + 2 * BF, Xhi, Xlo);
        }
        for (int l = 0; l < LAYERS; ++l, ++ls) {
            const ushort* axh;
            const ushort* axl;
            if (l > 0)        { axh = Hhi + (size_t)(l - 1) * BF; axl = Hlo + (size_t)(l - 1) * BF; }
            else if (!dec || t == HISTLEN) { axh = Xhi; axl = Xlo; }
            else              { axh = Hhi + 2 * BF; axl = Hlo + 2 * BF; }

            gemm_cell<<<ggrid, 256, 0, stream>>>(
                axh, axl, Whi + (size_t)(2 * l) * Wsl, Wlo + (size_t)(2 * l) * Wsl,
                Hhi + (size_t)l * BF, Hlo + (size_t)l * BF,
                Whi + (size_t)(2 * l + 1) * Wsl, Wlo + (size_t)(2 * l + 1) * Wsl,
                gp, cnt + ls * 32,
                bih + l * NG, bhh + l * NG,
                c + (size_t)l * BF, Hhi + (size_t)l * BF, Hlo + (size_t)l * BF,
                (dec && l == LAYERS - 1) ? out : nullptr, dec ? t - HISTLEN : 0, fut);
        }
    }
}

// Round 6
// 5803.077 us; speedup vs baseline: 4.0671x; 4.0671x over previous
//
#include <hip/hip_runtime.h>

// LSTM encoder-decoder B=512 F=1024 HIST=20 FUT=30 L=3 (fp32 in/out).
// Round 9: REVERT to round-6 verified base (5798us): 128^2 tiles, z=4 split-K,
//   2 blocks/CU, counted-vmcnt(8) double-buffer pipeline, pre-split bf16
//   weights, XCD remap. Separate cell_fuse kernel (now f32x4-vectorized).
//   Round-7/8 post-mortem: BOTH cross-block fusion attempts are fabric
//   disasters — threadfence = per-block L2 writeback (197us, MfmaUtil 2-5%);
//   agent-scope relaxed stores/loads = uncached scattered 4B traffic (185us,
//   FETCH 87MB vs 38MB unique). XCD-local sc0 fusion would tie correctness to
//   the undocumented blockIdx->XCD map (G16 violation). Fusion abandoned.
//   Structural state: GEMM at 43% MFMA util = m97-structure ceiling (floor
//   12.4us, measured ~29us); cell_fuse at HBM roofline (~42MB @ 6TB/s).

#define BDIM 512
#define FDIM 1024
#define HISTLEN 20
#define LAYERS 3
#define NG 4096
#define KD 1024
#define KSTEPS 16   // 512 k per block-chunk / BK=32

typedef __attribute__((ext_vector_type(8))) short short8;   // 8 bf16 = 4 VGPRs
typedef __attribute__((ext_vector_type(4))) float f32x4;    // MFMA accumulator
typedef __attribute__((ext_vector_type(4))) unsigned short u16x4;

__device__ __forceinline__ float sigf(float x) { return 1.f / (1.f + __expf(-x)); }
__device__ __forceinline__ float tanh_fast(float x) {
    float e = __expf(-2.f * fabsf(x));
    float r = (1.f - e) / (1.f + e);
    return copysignf(r, x);
}
__device__ __forceinline__ ushort bfhi(float w) { return (ushort)(__float_as_uint(w) >> 16); }
__device__ __forceinline__ float hif(float w) { return __uint_as_float(__float_as_uint(w) & 0xFFFF0000u); }
__device__ __forceinline__ ushort bflo(float w) { return bfhi(w - hif(w)); }

__device__ __forceinline__ void gl16(const ushort* g, ushort* l) {
    __builtin_amdgcn_global_load_lds(
        (const __attribute__((address_space(1))) unsigned int*)g,
        (__attribute__((address_space(3))) unsigned int*)l, 16, 0, 0);
}

// ---------------- one-time weight pre-split: fp32 W -> bf16 hi/lo --------------
// slot = l*2+s (s=0 Wih, 1 Whh), each slot 2^22 elems.
__global__ void prep_w(const float* __restrict__ Wih, const float* __restrict__ Whh,
                       ushort* __restrict__ Whi, ushort* __restrict__ Wlo)
{
    size_t i4 = ((size_t)blockIdx.x * 256 + threadIdx.x) * 4;
    size_t slot = i4 >> 22;
    size_t off  = i4 & 0x3FFFFFu;
    const float* src = ((slot & 1) ? Whh : Wih) + ((slot >> 1) << 22) + off;
    float4 v = *(const float4*)src;
    u16x4 hi, lo;
    #pragma unroll
    for (int e = 0; e < 4; ++e) {
        float w = ((const float*)&v)[e];
        unsigned u = __float_as_uint(w);
        hi[e] = (ushort)(u >> 16);
        float r = w - __uint_as_float(u & 0xFFFF0000u);
        lo[e] = (ushort)(__float_as_uint(r) >> 16);
    }
    *(u16x4*)(Whi + i4) = hi;
    *(u16x4*)(Wlo + i4) = lo;
}

// ---------------- GEMM: gp[z][512,4096] partial = A(s) @ W(s)^T over k-half ----
// z = kh*2 + s. All operands pre-split bf16. Tiles 128x128, BK=32, 256 thr,
// 512 blocks = 2/CU. LDS linear [128][32] per tile, XOR-swizzle chunk^=(row>>1)&3
// applied on global SOURCE addr (stage) and on ds_read addr (both-sides, m173).
// Block remap: lb -> (xcd = lb&7, j = lb>>3); z = xcd>>1, x = (xcd&1)*16+(j&15),
// y = j>>4. Bijective; each XCD owns one z-slice and a 16-wide x-band.
__global__ __launch_bounds__(256, 2) void gemm_split(
    const ushort* __restrict__ A0hi, const ushort* __restrict__ A0lo,
    const ushort* __restrict__ W0hi, const ushort* __restrict__ W0lo,
    const ushort* __restrict__ A1hi, const ushort* __restrict__ A1lo,
    const ushort* __restrict__ W1hi, const ushort* __restrict__ W1lo,
    float* __restrict__ gp)
{
    // [buf][tile: Ahi,Alo,Whi,Wlo][128*32 bf16] = 64 KB total
    __shared__ __attribute__((aligned(16))) ushort lds[2][4][4096];

    const int lb  = blockIdx.x + 32 * blockIdx.y + 128 * blockIdx.z;  // 0..511
    const int xcd = lb & 7;
    const int jj  = lb >> 3;                  // 0..63 (slot within XCD)
    const int z   = xcd >> 1;                 // 2 XCDs per z-slice
    const int bx  = (xcd & 1) * 16 + (jj & 15);
    const int by  = jj >> 4;

    const int s  = z & 1;
    const int kh = z >> 1;
    const ushort* Ahi = s ? A1hi : A0hi;
    const ushort* Alo = s ? A1lo : A0lo;
    const ushort* Whi = s ? W1hi : W0hi;
    const ushort* Wlo = s ? W1lo : W0lo;
    float* out = gp + (size_t)z * BDIM * NG;

    const int tid = threadIdx.x;
    const int m0 = by * 128;
    const int n0 = bx * 128;

    // staging: thread -> (row=tid>>2, chunk=tid&3), pass 1 adds 64 rows.
    // source chunk pre-swizzled: chunk' = chunk ^ ((row>>1)&3)
    const int srow = tid >> 2;
    const int scol = ((tid & 3) ^ ((srow >> 1) & 3)) << 3;   // bf16 elems
    const int kbeg = kh * (KD / 2);

    const ushort* pAhi = Ahi + (size_t)(m0 + srow) * KD + kbeg + scol;
    const ushort* pAlo = Alo + (size_t)(m0 + srow) * KD + kbeg + scol;
    const ushort* pWhi = Whi + (size_t)(n0 + srow) * KD + kbeg + scol;
    const ushort* pWlo = Wlo + (size_t)(n0 + srow) * KD + kbeg + scol;
    const int rstep = 64 * KD;

    const int lane = tid & 63;
    const int wid  = tid >> 6;
    const int wm = (wid & 1) * 64;
    const int wn = (wid >> 1) * 64;
    const int frow = lane & 15;
    const int oct  = lane >> 4;

    int a_e[4], w_e[4];   // ushort-elem offsets within a tile (swizzled read)
    #pragma unroll
    for (int i = 0; i < 4; ++i) {
        int ra = wm + i * 16 + frow;
        a_e[i] = ra * 32 + (((oct ^ (ra >> 1)) & 3) << 3);
        int rw = wn + i * 16 + frow;
        w_e[i] = rw * 32 + (((oct ^ (rw >> 1)) & 3) << 3);
    }

    f32x4 acc[4][4] = {};

    auto STAGE = [&](ushort* buf, int kk) {   // 8 x global_load_lds (16B each)
        ushort* d0 = buf + tid * 8;           // chunks 0..255
        gl16(pAhi + kk,         d0);
        gl16(pAlo + kk,         d0 + 4096);
        gl16(pWhi + kk,         d0 + 8192);
        gl16(pWlo + kk,         d0 + 12288);
        ushort* d1 = d0 + 2048;               // chunks 256..511 (rows +64)
        gl16(pAhi + rstep + kk, d1);
        gl16(pAlo + rstep + kk, d1 + 4096);
        gl16(pWhi + rstep + kk, d1 + 8192);
        gl16(pWlo + rstep + kk, d1 + 12288);
    };

    auto COMPUTE = [&](const ushort* buf) {
        short8 fah[4], fal[4], fbh[4], fbl[4];
        #pragma unroll
        for (int i = 0; i < 4; ++i) {
            fah[i] = *(const short8*)(buf + a_e[i]);
            fal[i] = *(const short8*)(buf + 4096 + a_e[i]);
            fbh[i] = *(const short8*)(buf + 8192 + w_e[i]);
            fbl[i] = *(const short8*)(buf + 12288 + w_e[i]);
        }
        asm volatile("s_waitcnt lgkmcnt(0)" ::: "memory");
        __builtin_amdgcn_sched_barrier(0);
        __builtin_amdgcn_s_barrier();         // barrier B: all reads of buf done
        __builtin_amdgcn_sched_barrier(0);
        __builtin_amdgcn_s_setprio(1);
        #pragma unroll
        for (int j = 0; j < 4; ++j) {
            #pragma unroll
            for (int i = 0; i < 4; ++i) {
                acc[i][j] = __builtin_amdgcn_mfma_f32_16x16x32_bf16(fah[i], fbh[j], acc[i][j], 0, 0, 0);
                acc[i][j] = __builtin_amdgcn_mfma_f32_16x16x32_bf16(fal[i], fbh[j], acc[i][j], 0, 0, 0);
                acc[i][j] = __builtin_amdgcn_mfma_f32_16x16x32_bf16(fah[i], fbl[j], acc[i][j], 0, 0, 0);
            }
        }
        __builtin_amdgcn_s_setprio(0);
    };

    STAGE(&lds[0][0][0], 0);                  // prologue: tile 0 in flight (8)
    #pragma unroll 1
    for (int t = 0; t < KSTEPS - 1; ++t) {
        // issue t+1 (safe: barrier B of t-1 proved all reads of this buf done)
        STAGE(&lds[(t + 1) & 1][0][0], (t + 1) * 32);
        asm volatile("s_waitcnt vmcnt(8)" ::: "memory");   // my tile-t loads landed
        __builtin_amdgcn_sched_barrier(0);
        __builtin_amdgcn_s_barrier();         // barrier A: everyone's tile-t landed
        __builtin_amdgcn_sched_barrier(0);
        COMPUTE(&lds[t & 1][0][0]);
    }
    asm volatile("s_waitcnt vmcnt(0)" ::: "memory");
    __builtin_amdgcn_s_barrier();
    COMPUTE(&lds[(KSTEPS - 1) & 1][0][0]);

    // C/D layout: row=(lane>>4)*4+reg, col=lane&15 (verified m89/m91)
    #pragma unroll
    for (int i = 0; i < 4; ++i) {
        #pragma unroll
        for (int j = 0; j < 4; ++j) {
            int col = n0 + wn + j * 16 + frow;
            #pragma unroll
            for (int r = 0; r < 4; ++r) {
                int row = m0 + wm + i * 16 + oct * 4 + r;
                out[(size_t)row * NG + col] = acc[i][j][r];
            }
        }
    }
}

// ---------------- elementwise cell update (sum 4 partials + biases) ------------
// f32x4-vectorized: 4 consecutive features per thread, identical bytes, 4x fewer
// memory instructions. grid = B*F/4 threads.
__global__ void cell_fuse(const float* __restrict__ gp,
                          const float* __restrict__ bi, const float* __restrict__ bh,
                          float* __restrict__ c,
                          ushort* __restrict__ Hhi, ushort* __restrict__ Hlo,
                          float* __restrict__ y, int t, int fut)
{
    const size_t MN = (size_t)BDIM * NG;
    int v = blockIdx.x * blockDim.x + threadIdx.x;     // < B*F/4
    int b = v >> 8, f4 = (v & 255) * 4;
    const size_t rowb = (size_t)b * NG;

    f32x4 g[4];
    #pragma unroll
    for (int gq = 0; gq < 4; ++gq)
        g[gq] = *(const f32x4*)(bi + gq * FDIM + f4) + *(const f32x4*)(bh + gq * FDIM + f4);
    #pragma unroll
    for (int zz = 0; zz < 4; ++zz) {
        const float* gz = gp + (size_t)zz * MN + rowb;
        #pragma unroll
        for (int gq = 0; gq < 4; ++gq)
            g[gq] += *(const f32x4*)(gz + gq * FDIM + f4);
    }

    const int idx = b * FDIM + f4;
    f32x4 cv = *(const f32x4*)(c + idx);
    f32x4 cn, hn;
    #pragma unroll
    for (int e = 0; e < 4; ++e) {
        cn[e] = sigf(g[1][e]) * cv[e] + sigf(g[0][e]) * tanh_fast(g[2][e]);
        hn[e] = sigf(g[3][e]) * tanh_fast(cn[e]);
    }
    *(f32x4*)(c + idx) = cn;
    u16x4 hh, hl;
    #pragma unroll
    for (int e = 0; e < 4; ++e) { hh[e] = bfhi(hn[e]); hl[e] = bflo(hn[e]); }
    *(u16x4*)(Hhi + idx) = hh;
    *(u16x4*)(Hlo + idx) = hl;
    if (y) {
        #pragma unroll
        for (int e = 0; e < 4; ++e) y[(size_t)(idx + e) * fut + t] = hn[e];
    }
}

// x_t from seq [B,F,HIST] -> split bf16
__global__ void pack_split(const float* __restrict__ seq,
                           ushort* __restrict__ Xhi, ushort* __restrict__ Xlo, int t)
{
    int idx = blockIdx.x * blockDim.x + threadIdx.x;
    float v = seq[(size_t)idx * HISTLEN + t];
    Xhi[idx] = bfhi(v);
    Xlo[idx] = bflo(v);
}

// fp32 vector -> split bf16 (decoder t=0 input = c[2])
__global__ void split_vec(const float* __restrict__ src,
                          ushort* __restrict__ hi, ushort* __restrict__ lo)
{
    int idx = blockIdx.x * blockDim.x + threadIdx.x;
    float v = src[idx];
    hi[idx] = bfhi(v);
    lo[idx] = bflo(v);
}

extern "C" void kernel_launch(void* const* d_in, const int* in_sizes, int n_in,
                              void* d_out, int out_size, void* d_ws, size_t ws_size,
                              hipStream_t stream)
{
    const float* seq = (const float*)d_in[0];
    const float* Wih = (const float*)d_in[1];
    const float* Whh = (const float*)d_in[2];
    const float* bih = (const float*)d_in[3];
    const float* bhh = (const float*)d_in[4];
    float* out = (float*)d_out;

    const int fut = out_size / (BDIM * FDIM);           // 30
    const size_t BF = (size_t)BDIM * FDIM;
    const size_t MN = (size_t)BDIM * NG;
    const size_t Wsl = (size_t)1 << 22;                 // elems per (l,s) weight slot

    // ws: c[3BF]f32 | Hhi[3BF]u16 | Hlo | Xhi[BF]u16 | Xlo | gp[4*MN]f32 |
    //     Whi[6*Wsl]u16 | Wlo[6*Wsl]u16   (total ~149 MiB)
    float*  c   = (float*)d_ws;
    ushort* Hhi = (ushort*)(c + LAYERS * BF);
    ushort* Hlo = Hhi + LAYERS * BF;
    ushort* Xhi = Hlo + LAYERS * BF;
    ushort* Xlo = Xhi + BF;
    float*  gp  = (float*)(Xlo + BF);
    ushort* Whi = (ushort*)(gp + 4 * MN);
    ushort* Wlo = Whi + 6 * Wsl;

    const size_t need = (size_t)((char*)(Wlo + 6 * Wsl) - (char*)d_ws);
    if (ws_size < need) return;                         // clean fail, no OOB

    hipMemsetAsync(d_ws, 0, LAYERS * BF * 8, stream);   // zero c, Hhi, Hlo
    prep_w<<<24576, 256, 0, stream>>>(Wih, Whh, Whi, Wlo);

    dim3 ggrid(NG / 128, BDIM / 128, 4);                // (32, 4, 4) = 512 WGs
    const int cgrid = (int)(BF / 256);
    const int vgrid = (int)(BF / 1024);                 // cell_fuse: 4 elems/thr

    for (int t = 0; t < HISTLEN + fut; ++t) {
        const bool dec = (t >= HISTLEN);
        if (!dec) {
            pack_split<<<cgrid, 256, 0, stream>>>(seq, Xhi, Xlo, t);
        } else if (t == HISTLEN) {
            split_vec<<<cgrid, 256, 0, stream>>>(c + 2 * BF, Xhi, Xlo);
        }
        for (int l = 0; l < LAYERS; ++l) {
            const ushort* axh;
            const ushort* axl;
            if (l > 0)        { axh = Hhi + (size_t)(l - 1) * BF; axl = Hlo + (size_t)(l - 1) * BF; }
            else if (!dec || t == HISTLEN) { axh = Xhi; axl = Xlo; }
            else              { axh = Hhi + 2 * BF; axl = Hlo + 2 * BF; }

            gemm_split<<<ggrid, 256, 0, stream>>>(
                axh, axl, Whi + (size_t)(2 * l) * Wsl, Wlo + (size_t)(2 * l) * Wsl,
                Hhi + (size_t)l * BF, Hlo + (size_t)l * BF,
                Whi + (size_t)(2 * l + 1) * Wsl, Wlo + (size_t)(2 * l + 1) * Wsl,
                gp);

            cell_fuse<<<vgrid, 256, 0, stream>>>(
                gp, bih + l * NG, bhh + l * NG,
                c + (size_t)l * BF, Hhi + (size_t)l * BF, Hlo + (size_t)l * BF,
                (dec && l == LAYERS - 1) ? out : nullptr, dec ? t - HISTLEN : 0, fut);
        }
    }
}